// Round 7
// baseline (194.482 us; speedup 1.0000x reference)
//
#include <hip/hip_runtime.h>
#include <hip/hip_bf16.h>

typedef __attribute__((ext_vector_type(8))) unsigned short ushort8;
typedef __attribute__((ext_vector_type(4))) unsigned short ushort4v;
typedef __attribute__((ext_vector_type(8))) short short8v;
typedef __attribute__((ext_vector_type(4))) float f32x4;

__device__ __forceinline__ float bf2f(unsigned short u){
  union { unsigned int i; float f; } x; x.i = ((unsigned int)u) << 16; return x.f;
}
__device__ __forceinline__ unsigned short f2bf(float f){
  __hip_bfloat16 h = __float2bfloat16(f);
  return *reinterpret_cast<unsigned short*>(&h);
}

// ---- prep: col7/val7/dvec via two binary searches over sorted row[]; zero g ----
__global__ void prep_k(const int* __restrict__ row, const int* __restrict__ colx,
                       const float* __restrict__ vals, int nnz,
                       int* __restrict__ col7, float* __restrict__ val7,
                       float* __restrict__ dvec, float* __restrict__ g, int V, int GN){
  int v = blockIdx.x*256 + threadIdx.x;
  if (v < GN) g[v] = 0.f;
  if (v >= V) return;
  int lo = 0, hi = nnz;
  while (lo < hi){ int m = (lo+hi)>>1; if (row[m] < v) lo = m+1; else hi = m; }
  int e0 = lo;
  int lo2 = e0; hi = nnz;
  while (lo2 < hi){ int m = (lo2+hi)>>1; if (row[m] < v+1) lo2 = m+1; else hi = m; }
  int e1 = lo2;
  float s = 0.f;
  #pragma unroll
  for (int i=0;i<7;i++){
    int e = e0 + i;
    int c  = (e < e1) ? colx[e] : 0;
    float wv = (e < e1) ? vals[e] : 0.f;
    col7[v*7+i] = c; val7[v*7+i] = wv; s += wv;
  }
  dvec[v] = s;
}

// ---- layer1: 8 threads per row (v,b); h1[(v*16+b)*64+c] = relu(spmm(x)@W1^T + d*b1) ----
__global__ void spmm_lin1_k(const float* __restrict__ x, const int* __restrict__ col7,
    const float* __restrict__ val7, const float* __restrict__ d,
    const float* __restrict__ W1, const float* __restrict__ b1,
    unsigned short* __restrict__ out, int V, int R){
  __shared__ float sW[192];
  __shared__ float sB[64];
  int tid = threadIdx.x;
  if (tid < 192) sW[tid] = W1[tid];
  if (tid < 64)  sB[tid] = b1[tid];
  __syncthreads();
  int idx = blockIdx.x*256 + tid;
  if (idx >= R*8) return;
  int cg = idx & 7; int r = idx >> 3;
  int b = r & 15;   int v = r >> 4;
  float s0=0.f, s1=0.f, s2=0.f;
  #pragma unroll
  for (int i=0;i<7;i++){
    int c = col7[v*7+i]; float wv = val7[v*7+i];
    const float* xr = x + ((size_t)b*V + c)*3;
    s0 += wv*xr[0]; s1 += wv*xr[1]; s2 += wv*xr[2];
  }
  float dv = d[v];
  ushort8 o;
  #pragma unroll
  for (int k=0;k<8;k++){
    int c = cg*8 + k;
    float acc = dv*sB[c] + s0*sW[c*3] + s1*sW[c*3+1] + s2*sW[c*3+2];
    o[k] = f2bf(fmaxf(acc, 0.f));
  }
  *reinterpret_cast<ushort8*>(out + (size_t)r*64 + cg*8) = o;
}

// ---- layer-2: [V][16][64] layout; gather = contiguous 2KB neighbor blocks, col7 scalar ----
template<int G>
__global__ __launch_bounds__(256) void lin2_spmm_k(const unsigned short* __restrict__ in,
    const float* __restrict__ W, const float* __restrict__ bias,
    const int* __restrict__ col7, const float* __restrict__ val7,
    const float* __restrict__ dvec, unsigned short* __restrict__ out, int R, int V){
  constexpr int K = 64, N = 64, KP = K + 8, NF = N/16;
  __shared__ unsigned short sW[N * KP];
  __shared__ float sB[N];
  int tid = threadIdx.x;
  for (int i = tid*4; i < N*K; i += 1024){
    const float4 wv = *reinterpret_cast<const float4*>(W + i);
    int n = i / K, k = i - n*K;
    unsigned short* dst = &sW[n*KP + k];
    dst[0] = f2bf(wv.x); dst[1] = f2bf(wv.y); dst[2] = f2bf(wv.z); dst[3] = f2bf(wv.w);
  }
  if (tid < N) sB[tid] = bias[tid];
  __syncthreads();

  const int wave = tid >> 6, lane = tid & 63;
  const int l15 = lane & 15, lg = lane >> 4;
  const unsigned short* aBase = &sW[l15*KP + lg*8];
  const size_t laneoff = (size_t)l15*64 + lg*8;   // b=l15 row offset within a 1024-elem v-block

  for (int t = 0; t < G; ++t){
    int rbase = (blockIdx.x*G + t)*128 + wave*32;
    if (rbase >= R) break;
    int v0 = __builtin_amdgcn_readfirstlane(min(rbase >> 4, V-1));
    int v1 = __builtin_amdgcn_readfirstlane(min((rbase >> 4) + 1, V-1));
    int c0a[7], c1a[7]; float w0a[7], w1a[7];
    #pragma unroll
    for (int i=0;i<7;i++){
      c0a[i] = col7[v0*7+i]; w0a[i] = val7[v0*7+i];
      c1a[i] = col7[v1*7+i]; w1a[i] = val7[v1*7+i];
    }
    f32x4 acc[NF][2];
    #pragma unroll
    for (int nf=0; nf<NF; ++nf){ acc[nf][0]=(f32x4)0.f; acc[nf][1]=(f32x4)0.f; }
    #pragma unroll
    for (int ks=0; ks<2; ++ks){
      float a0[8], a1[8];
      #pragma unroll
      for (int k=0;k<8;k++){ a0[k]=0.f; a1[k]=0.f; }
      #pragma unroll
      for (int i=0;i<7;i++){
        ushort8 g0 = *reinterpret_cast<const ushort8*>(in + (size_t)c0a[i]*1024 + laneoff + ks*32);
        ushort8 g1 = *reinterpret_cast<const ushort8*>(in + (size_t)c1a[i]*1024 + laneoff + ks*32);
        #pragma unroll
        for (int k=0;k<8;k++){ a0[k] += w0a[i]*bf2f(g0[k]); a1[k] += w1a[i]*bf2f(g1[k]); }
      }
      short8v b0, b1;
      #pragma unroll
      for (int k=0;k<8;k++){ b0[k]=(short)f2bf(a0[k]); b1[k]=(short)f2bf(a1[k]); }
      #pragma unroll
      for (int nf=0; nf<NF; ++nf){
        short8v a = *reinterpret_cast<const short8v*>(aBase + nf*16*KP + ks*32);
        acc[nf][0] = __builtin_amdgcn_mfma_f32_16x16x32_bf16(a, b0, acc[nf][0], 0,0,0);
        acc[nf][1] = __builtin_amdgcn_mfma_f32_16x16x32_bf16(a, b1, acc[nf][1], 0,0,0);
      }
    }
    float dd0 = dvec[v0], dd1 = dvec[v1];
    #pragma unroll
    for (int rr=0; rr<2; ++rr){
      int r = rbase + rr*16 + l15;
      if (r >= R) continue;
      float ds = rr ? dd1 : dd0;
      #pragma unroll
      for (int nf=0; nf<NF; ++nf){
        int nb = nf*16 + lg*4;
        ushort4v o;
        #pragma unroll
        for (int reg=0; reg<4; ++reg){
          float v = fmaxf(acc[nf][rr][reg] + ds*sB[nb+reg], 0.f);
          o[reg] = f2bf(v);
        }
        *reinterpret_cast<ushort4v*>(out + (size_t)r*N + nb) = o;
      }
    }
  }
}

// ---- layer-3 + mean: b=l15 so the v-sum is lane-local; register acc -> LDS -> global ----
template<int G>
__global__ __launch_bounds__(256) void lin3_spmm_mean_k(const unsigned short* __restrict__ in,
    const float* __restrict__ W, const float* __restrict__ bias,
    const int* __restrict__ col7, const float* __restrict__ val7,
    const float* __restrict__ dvec, float* __restrict__ g, int R, int V){
  constexpr int K = 64, N = 128, KP = K + 8, NF = N/16;
  __shared__ unsigned short sW[N * KP];
  __shared__ float sB[N];
  __shared__ float gPart[16*132];
  int tid = threadIdx.x;
  for (int i = tid*4; i < N*K; i += 1024){
    const float4 wv = *reinterpret_cast<const float4*>(W + i);
    int n = i / K, k = i - n*K;
    unsigned short* dst = &sW[n*KP + k];
    dst[0] = f2bf(wv.x); dst[1] = f2bf(wv.y); dst[2] = f2bf(wv.z); dst[3] = f2bf(wv.w);
  }
  if (tid < N) sB[tid] = bias[tid];
  for (int i = tid; i < 16*132; i += 256) gPart[i] = 0.f;
  __syncthreads();

  const int wave = tid >> 6, lane = tid & 63;
  const int l15 = lane & 15, lg = lane >> 4;
  const unsigned short* aBase = &sW[l15*KP + lg*8];
  const size_t laneoff = (size_t)l15*64 + lg*8;

  float racc[NF][4];
  #pragma unroll
  for (int nf=0;nf<NF;++nf)
    #pragma unroll
    for (int reg=0;reg<4;++reg) racc[nf][reg] = 0.f;

  for (int t = 0; t < G; ++t){
    int rbase = (blockIdx.x*G + t)*128 + wave*32;
    if (rbase >= R) break;
    int v0 = __builtin_amdgcn_readfirstlane(min(rbase >> 4, V-1));
    int v1 = __builtin_amdgcn_readfirstlane(min((rbase >> 4) + 1, V-1));
    int c0a[7], c1a[7]; float w0a[7], w1a[7];
    #pragma unroll
    for (int i=0;i<7;i++){
      c0a[i] = col7[v0*7+i]; w0a[i] = val7[v0*7+i];
      c1a[i] = col7[v1*7+i]; w1a[i] = val7[v1*7+i];
    }
    f32x4 acc[NF][2];
    #pragma unroll
    for (int nf=0; nf<NF; ++nf){ acc[nf][0]=(f32x4)0.f; acc[nf][1]=(f32x4)0.f; }
    #pragma unroll
    for (int ks=0; ks<2; ++ks){
      float a0[8], a1[8];
      #pragma unroll
      for (int k=0;k<8;k++){ a0[k]=0.f; a1[k]=0.f; }
      #pragma unroll
      for (int i=0;i<7;i++){
        ushort8 g0 = *reinterpret_cast<const ushort8*>(in + (size_t)c0a[i]*1024 + laneoff + ks*32);
        ushort8 g1 = *reinterpret_cast<const ushort8*>(in + (size_t)c1a[i]*1024 + laneoff + ks*32);
        #pragma unroll
        for (int k=0;k<8;k++){ a0[k] += w0a[i]*bf2f(g0[k]); a1[k] += w1a[i]*bf2f(g1[k]); }
      }
      short8v b0, b1;
      #pragma unroll
      for (int k=0;k<8;k++){ b0[k]=(short)f2bf(a0[k]); b1[k]=(short)f2bf(a1[k]); }
      #pragma unroll
      for (int nf=0; nf<NF; ++nf){
        short8v a = *reinterpret_cast<const short8v*>(aBase + nf*16*KP + ks*32);
        acc[nf][0] = __builtin_amdgcn_mfma_f32_16x16x32_bf16(a, b0, acc[nf][0], 0,0,0);
        acc[nf][1] = __builtin_amdgcn_mfma_f32_16x16x32_bf16(a, b1, acc[nf][1], 0,0,0);
      }
    }
    float d0 = dvec[v0], d1 = dvec[v1];
    bool ok0 = (rbase + l15) < R;
    bool ok1 = (rbase + 16 + l15) < R;
    #pragma unroll
    for (int nf=0; nf<NF; ++nf){
      #pragma unroll
      for (int reg=0; reg<4; ++reg){
        int c = nf*16 + lg*4 + reg;
        float v0f = fmaxf(acc[nf][0][reg] + d0*sB[c], 0.f);
        float v1f = fmaxf(acc[nf][1][reg] + d1*sB[c], 0.f);
        racc[nf][reg] += (ok0 ? v0f : 0.f) + (ok1 ? v1f : 0.f);
      }
    }
  }
  // per-block reduce: b = l15 fixed per lane, c fixed per (nf,lg,reg)
  #pragma unroll
  for (int nf=0; nf<NF; ++nf){
    #pragma unroll
    for (int reg=0; reg<4; ++reg){
      int c = nf*16 + lg*4 + reg;
      atomicAdd(&gPart[l15*132 + c], racc[nf][reg]);
    }
  }
  __syncthreads();
  for (int i = tid; i < 2048; i += 256){
    int b = i >> 7, c = i & 127;
    float val = gPart[b*132 + c];
    if (val != 0.f) atomicAdd(&g[i], val);
  }
}

// ---- fused VAE head: one block per batch element ----
__global__ __launch_bounds__(256) void head2_k(const float* __restrict__ g,
    const float* __restrict__ Wfc, const float* __restrict__ bfc,
    const float* __restrict__ Wmu, const float* __restrict__ bmu,
    const float* __restrict__ Wlv, const float* __restrict__ blv,
    const float* __restrict__ eps, const float* __restrict__ Wd1,
    const float* __restrict__ bd1, float* __restrict__ mu_out,
    float* __restrict__ lv_out, float* __restrict__ zp, float invV){
  int b = blockIdx.x;
  int tid = threadIdx.x;
  __shared__ float sG[128];
  __shared__ float sF[256];
  __shared__ float sMu[32];
  __shared__ float sLv[32];
  __shared__ float sZ[32];
  if (tid < 128) sG[tid] = g[b*128 + tid] * invV;
  __syncthreads();
  {
    const float4* wr = reinterpret_cast<const float4*>(Wfc + tid*128);
    float acc = bfc[tid];
    #pragma unroll 8
    for (int k4=0;k4<32;k4++){
      float4 wv = wr[k4];
      acc += sG[k4*4]*wv.x + sG[k4*4+1]*wv.y + sG[k4*4+2]*wv.z + sG[k4*4+3]*wv.w;
    }
    sF[tid] = fmaxf(acc, 0.f);
  }
  __syncthreads();
  if (tid < 64){
    int c = tid & 31;
    bool isMu = tid < 32;
    const float4* wr = reinterpret_cast<const float4*>((isMu ? Wmu : Wlv) + c*256);
    float acc = isMu ? bmu[c] : blv[c];
    #pragma unroll 8
    for (int k4=0;k4<64;k4++){
      float4 wv = wr[k4];
      acc += sF[k4*4]*wv.x + sF[k4*4+1]*wv.y + sF[k4*4+2]*wv.z + sF[k4*4+3]*wv.w;
    }
    if (isMu){ sMu[c] = acc; mu_out[b*32+c] = acc; }
    else {
      acc = fminf(20.f, fmaxf(-20.f, acc));
      sLv[c] = acc; lv_out[b*32+c] = acc;
    }
  }
  __syncthreads();
  if (tid < 32) sZ[tid] = sMu[tid] + eps[b*32+tid]*expf(0.5f*sLv[tid]);
  __syncthreads();
  if (tid < 128){
    const float* wr = Wd1 + tid*35;
    float acc = bd1[tid];
    #pragma unroll
    for (int k=0;k<32;k++) acc += sZ[k]*wr[k];
    zp[b*128 + tid] = acc;
  }
}

// ---- decoder layer 2: rows (v,b); B built on the fly, v uniform, b=l15 ----
__global__ __launch_bounds__(256) void lin_dec2z_k(const float* __restrict__ zp,
    const float* __restrict__ tmpl, const float* __restrict__ Wd1,
    const float* __restrict__ W, const float* __restrict__ bias,
    unsigned short* __restrict__ out, int R, int V, int Bn){
  constexpr int K = 128, N = 128, KP = K + 8, NF = N/16, KS = 4;
  __shared__ unsigned short sW[N * KP];
  __shared__ float sB[N];
  __shared__ float sZP[16*132];
  __shared__ float sWT[128*3];
  int tid = threadIdx.x;
  for (int i = tid*4; i < N*K; i += 1024){
    const float4 wv = *reinterpret_cast<const float4*>(W + i);
    int n = i / K, k = i - n*K;
    unsigned short* dst = &sW[n*KP + k];
    dst[0] = f2bf(wv.x); dst[1] = f2bf(wv.y); dst[2] = f2bf(wv.z); dst[3] = f2bf(wv.w);
  }
  if (tid < N) sB[tid] = bias[tid];
  for (int i = tid; i < Bn*128; i += 256){ int b = i>>7, c = i&127; sZP[b*132+c] = zp[i]; }
  if (tid < 128){
    sWT[tid*3+0] = Wd1[tid*35+32];
    sWT[tid*3+1] = Wd1[tid*35+33];
    sWT[tid*3+2] = Wd1[tid*35+34];
  }
  __syncthreads();

  const int wave = tid >> 6, lane = tid & 63;
  const int l15 = lane & 15, lg = lane >> 4;
  const int rbase = blockIdx.x*128 + wave*32;
  int v0 = __builtin_amdgcn_readfirstlane(min(rbase >> 4, V-1));
  int v1 = __builtin_amdgcn_readfirstlane(min((rbase >> 4) + 1, V-1));
  float t0x = tmpl[v0*3], t0y = tmpl[v0*3+1], t0z = tmpl[v0*3+2];
  float t1x = tmpl[v1*3], t1y = tmpl[v1*3+1], t1z = tmpl[v1*3+2];
  const float* zrow = sZP + l15*132;
  const unsigned short* aBase = &sW[l15*KP + lg*8];

  f32x4 acc[NF][2];
  #pragma unroll
  for (int nf=0; nf<NF; ++nf){ acc[nf][0]=(f32x4)0.f; acc[nf][1]=(f32x4)0.f; }

  #pragma unroll
  for (int ks=0; ks<KS; ++ks){
    short8v b0, b1;
    #pragma unroll
    for (int k=0;k<8;k++){
      int c = lg*8 + ks*32 + k;
      const float* wt = sWT + c*3;
      float zc = zrow[c];
      b0[k] = (short)f2bf(fmaxf(zc + t0x*wt[0] + t0y*wt[1] + t0z*wt[2], 0.f));
      b1[k] = (short)f2bf(fmaxf(zc + t1x*wt[0] + t1y*wt[1] + t1z*wt[2], 0.f));
    }
    #pragma unroll
    for (int nf=0; nf<NF; ++nf){
      short8v a = *reinterpret_cast<const short8v*>(aBase + nf*16*KP + ks*32);
      acc[nf][0] = __builtin_amdgcn_mfma_f32_16x16x32_bf16(a, b0, acc[nf][0], 0,0,0);
      acc[nf][1] = __builtin_amdgcn_mfma_f32_16x16x32_bf16(a, b1, acc[nf][1], 0,0,0);
    }
  }

  #pragma unroll
  for (int rr=0; rr<2; ++rr){
    int r = rbase + rr*16 + l15;
    if (r >= R) continue;
    #pragma unroll
    for (int nf=0; nf<NF; ++nf){
      int nb = nf*16 + lg*4;
      ushort4v o;
      #pragma unroll
      for (int reg=0; reg<4; ++reg){
        float v = fmaxf(acc[nf][rr][reg] + sB[nb + reg], 0.f);
        o[reg] = f2bf(v);
      }
      *reinterpret_cast<ushort4v*>(out + (size_t)r*N + nb) = o;
    }
  }
}

// ---- decoder 3+4 fused: rows (v,b); recon[b*V+v] = tmpl + relu(in@Wd3^T+bd3)@Wd4^T+bd4 ----
__global__ __launch_bounds__(256) void lin_dec34_k(const unsigned short* __restrict__ in,
    const float* __restrict__ W3, const float* __restrict__ b3,
    const float* __restrict__ W4, const float* __restrict__ b4,
    const float* __restrict__ tmpl, float* __restrict__ out, int R, int V){
  constexpr int K = 128, N = 64, KP = K + 8, NF = N/16, KS = K/32;
  __shared__ unsigned short sW[N * KP];
  __shared__ float sB3[N];
  __shared__ float sW4[3*64];
  int tid = threadIdx.x;
  for (int i = tid*4; i < N*K; i += 1024){
    const float4 wv = *reinterpret_cast<const float4*>(W3 + i);
    int n = i / K, k = i - n*K;
    unsigned short* dst = &sW[n*KP + k];
    dst[0] = f2bf(wv.x); dst[1] = f2bf(wv.y); dst[2] = f2bf(wv.z); dst[3] = f2bf(wv.w);
  }
  if (tid < N) sB3[tid] = b3[tid];
  if (tid < 192) sW4[tid] = W4[tid];
  __syncthreads();

  const int wave = tid >> 6, lane = tid & 63;
  const int l15 = lane & 15, lg = lane >> 4;
  const int rbase = blockIdx.x*128 + wave*32;

  int r0c = min(rbase + l15,      R-1);
  int r1c = min(rbase + 16 + l15, R-1);
  const unsigned short* bp0 = in + (size_t)r0c*K + lg*8;
  const unsigned short* bp1 = in + (size_t)r1c*K + lg*8;
  const unsigned short* aBase = &sW[l15*KP + lg*8];

  f32x4 acc[NF][2];
  #pragma unroll
  for (int nf=0; nf<NF; ++nf){ acc[nf][0]=(f32x4)0.f; acc[nf][1]=(f32x4)0.f; }

  #pragma unroll
  for (int ks=0; ks<KS; ++ks){
    short8v b0 = *reinterpret_cast<const short8v*>(bp0 + ks*32);
    short8v b1 = *reinterpret_cast<const short8v*>(bp1 + ks*32);
    #pragma unroll
    for (int nf=0; nf<NF; ++nf){
      short8v a = *reinterpret_cast<const short8v*>(aBase + nf*16*KP + ks*32);
      acc[nf][0] = __builtin_amdgcn_mfma_f32_16x16x32_bf16(a, b0, acc[nf][0], 0,0,0);
      acc[nf][1] = __builtin_amdgcn_mfma_f32_16x16x32_bf16(a, b1, acc[nf][1], 0,0,0);
    }
  }

  #pragma unroll
  for (int rr=0; rr<2; ++rr){
    int r = rbase + rr*16 + l15;
    int vu = __builtin_amdgcn_readfirstlane(min((rbase >> 4) + rr, V-1));
    float p0 = 0.f, p1 = 0.f, p2 = 0.f;
    #pragma unroll
    for (int nf=0; nf<NF; ++nf){
      #pragma unroll
      for (int reg=0; reg<4; ++reg){
        int c = nf*16 + lg*4 + reg;
        float h = fmaxf(acc[nf][rr][reg] + sB3[c], 0.f);
        p0 += h*sW4[c]; p1 += h*sW4[64+c]; p2 += h*sW4[128+c];
      }
    }
    p0 += __shfl_xor(p0,16); p0 += __shfl_xor(p0,32);
    p1 += __shfl_xor(p1,16); p1 += __shfl_xor(p1,32);
    p2 += __shfl_xor(p2,16); p2 += __shfl_xor(p2,32);
    if (lg == 0 && r < R){
      size_t o = ((size_t)l15*V + vu)*3;   // b = l15
      out[o+0] = tmpl[vu*3+0] + p0 + b4[0];
      out[o+1] = tmpl[vu*3+1] + p1 + b4[1];
      out[o+2] = tmpl[vu*3+2] + p2 + b4[2];
    }
  }
}

extern "C" void kernel_launch(void* const* d_in, const int* in_sizes, int n_in,
                              void* d_out, int out_size, void* d_ws, size_t ws_size,
                              hipStream_t stream){
  const float* x    = (const float*)d_in[0];
  const float* eps  = (const float*)d_in[1];
  const int*   row  = (const int*)d_in[2];
  const int*   colx = (const int*)d_in[3];
  const float* vals = (const float*)d_in[4];
  const float* tmpl = (const float*)d_in[5];
  const float* W1 = (const float*)d_in[6];  const float* b1 = (const float*)d_in[7];
  const float* W2 = (const float*)d_in[8];  const float* b2 = (const float*)d_in[9];
  const float* W3 = (const float*)d_in[10]; const float* b3 = (const float*)d_in[11];
  const float* Wfc= (const float*)d_in[12]; const float* bfc= (const float*)d_in[13];
  const float* Wmu= (const float*)d_in[14]; const float* bmu= (const float*)d_in[15];
  const float* Wlv= (const float*)d_in[16]; const float* blv= (const float*)d_in[17];
  const float* Wd1= (const float*)d_in[18]; const float* bd1= (const float*)d_in[19];
  const float* Wd2= (const float*)d_in[20]; const float* bd2= (const float*)d_in[21];
  const float* Wd3= (const float*)d_in[22]; const float* bd3= (const float*)d_in[23];
  const float* Wd4= (const float*)d_in[24]; const float* bd4= (const float*)d_in[25];

  int V   = in_sizes[5] / 3;     // 10242
  int Bn  = in_sizes[1] / 32;    // 16
  int nnz = in_sizes[2];         // 71682
  int R   = Bn * V;              // 163872  (rows ordered (v,b): r = v*16 + b)

  // workspace layout
  char* w = (char*)d_ws;
  size_t off = 0;
  auto alloc = [&](size_t bytes)->char*{
    char* p = w + off; off = (off + bytes + 255) & ~(size_t)255; return p;
  };
  unsigned short* bufA = (unsigned short*)alloc((size_t)R * 128 * 2); // h1 (64ch) then hd2 (128ch)
  unsigned short* bufB = (unsigned short*)alloc((size_t)R * 64  * 2); // h2p (64ch)
  int*   col7 = (int*)alloc((size_t)V*7*4);
  float* val7 = (float*)alloc((size_t)V*7*4);
  float* dvec = (float*)alloc((size_t)V*4);
  float* g    = (float*)alloc((size_t)Bn*128*4);
  float* zp   = (float*)alloc((size_t)Bn*128*4);

  float* recon  = (float*)d_out;
  float* mu_out = recon + (size_t)R*3;
  float* lv_out = mu_out + (size_t)Bn*32;

  // prep (col7/val7/dvec + zero g)
  prep_k<<<(V+255)/256, 256, 0, stream>>>(row, colx, vals, nnz, col7, val7, dvec, g, V, Bn*128);

  // encoder
  spmm_lin1_k<<<(R*8+255)/256, 256, 0, stream>>>(x, col7, val7, dvec, W1, b1, bufA, V, R);
  lin2_spmm_k<2><<<(R+255)/256, 256, 0, stream>>>(bufA, W2, b2, col7, val7, dvec, bufB, R, V);
  lin3_spmm_mean_k<2><<<(R+255)/256, 256, 0, stream>>>(bufB, W3, b3, col7, val7, dvec, g, R, V);

  // head (feat/mu/lv/z/zpart)
  head2_k<<<Bn, 256, 0, stream>>>(g, Wfc, bfc, Wmu, bmu, Wlv, blv, eps, Wd1, bd1,
                                  mu_out, lv_out, zp, 1.0f/(float)V);

  // decoder
  lin_dec2z_k<<<(R+127)/128, 256, 0, stream>>>(zp, tmpl, Wd1, Wd2, bd2, bufA, R, V, Bn);
  lin_dec34_k<<<(R+127)/128, 256, 0, stream>>>(bufA, Wd3, bd3, Wd4, bd4, tmpl, recon, R, V);
}

// Round 8
// 145.029 us; speedup vs baseline: 1.3410x; 1.3410x over previous
//
#include <hip/hip_runtime.h>
#include <hip/hip_bf16.h>

typedef __attribute__((ext_vector_type(8))) unsigned short ushort8;
typedef __attribute__((ext_vector_type(4))) unsigned short ushort4v;
typedef __attribute__((ext_vector_type(8))) short short8v;
typedef __attribute__((ext_vector_type(4))) float f32x4;

__device__ __forceinline__ float bf2f(unsigned short u){
  union { unsigned int i; float f; } x; x.i = ((unsigned int)u) << 16; return x.f;
}
__device__ __forceinline__ unsigned short f2bf(float f){
  __hip_bfloat16 h = __float2bfloat16(f);
  return *reinterpret_cast<unsigned short*>(&h);
}

// ---- prep: col7/val7/dvec via two binary searches over sorted row[]; zero g ----
__global__ void prep_k(const int* __restrict__ row, const int* __restrict__ colx,
                       const float* __restrict__ vals, int nnz,
                       int* __restrict__ col7, float* __restrict__ val7,
                       float* __restrict__ dvec, float* __restrict__ g, int V, int GN){
  int v = blockIdx.x*256 + threadIdx.x;
  if (v < GN) g[v] = 0.f;
  if (v >= V) return;
  int lo = 0, hi = nnz;
  while (lo < hi){ int m = (lo+hi)>>1; if (row[m] < v) lo = m+1; else hi = m; }
  int e0 = lo;
  int lo2 = e0; hi = nnz;
  while (lo2 < hi){ int m = (lo2+hi)>>1; if (row[m] < v+1) lo2 = m+1; else hi = m; }
  int e1 = lo2;
  float s = 0.f;
  #pragma unroll
  for (int i=0;i<7;i++){
    int e = e0 + i;
    int c  = (e < e1) ? colx[e] : 0;
    float wv = (e < e1) ? vals[e] : 0.f;
    col7[v*7+i] = c; val7[v*7+i] = wv; s += wv;
  }
  dvec[v] = s;
}

// ---- fused: s = spmm(x) over C=3, then h1 = relu(s@W1^T + d[v]*b1), bf16 out (b-major rows) ----
__global__ void spmm_lin1_k(const float* __restrict__ x, const int* __restrict__ col7,
    const float* __restrict__ val7, const float* __restrict__ d,
    const float* __restrict__ W1, const float* __restrict__ b1,
    unsigned short* __restrict__ out, int V, int R){
  __shared__ float sW[192];
  __shared__ float sB[64];
  int tid = threadIdx.x;
  if (tid < 192) sW[tid] = W1[tid];
  if (tid < 64)  sB[tid] = b1[tid];
  __syncthreads();
  int r = blockIdx.x*256 + tid;
  if (r >= R) return;
  int b = r / V; int v = r - b*V;
  const float* xb = x + (size_t)b*V*3;
  int   cs[7]; float ws[7];
  #pragma unroll
  for (int i=0;i<7;i++){ cs[i] = col7[v*7+i]; ws[i] = val7[v*7+i]; }
  float s0=0.f, s1=0.f, s2=0.f;
  #pragma unroll
  for (int i=0;i<7;i++){
    const float* xr = xb + (size_t)cs[i]*3;
    s0 += ws[i]*xr[0]; s1 += ws[i]*xr[1]; s2 += ws[i]*xr[2];
  }
  float dv = d[v];
  unsigned short* orow = out + (size_t)r*64;
  #pragma unroll
  for (int cg=0; cg<8; ++cg){
    ushort8 o;
    #pragma unroll
    for (int k=0;k<8;k++){
      int c = cg*8 + k;
      float acc = dv*sB[c] + s0*sW[c*3] + s1*sW[c*3+1] + s2*sW[c*3+2];
      o[k] = f2bf(fmaxf(acc, 0.f));
    }
    *reinterpret_cast<ushort8*>(orow + cg*8) = o;
  }
}

// ---- SPMM deg-7, 8ch/thread, XCD-swizzled: each XCD owns 2 batch slices (L2-resident) ----
__global__ __launch_bounds__(256) void spmm8s_k(const unsigned short* __restrict__ in,
    unsigned short* __restrict__ out, const int* __restrict__ col7,
    const float* __restrict__ val7, int V, int NBperB){
  int p = blockIdx.x;
  int xcd = p & 7, q = p >> 3;
  int half = (q >= NBperB) ? 1 : 0;
  int off  = q - half*NBperB;
  int b = xcd + (half<<3);
  int j = off*256 + (int)threadIdx.x;
  if (j >= V*8) return;
  int cg = j & 7; int v = j >> 3;
  const unsigned short* base = in + (size_t)b*V*64 + cg*8;
  int cols[7]; float vv[7];
  #pragma unroll
  for (int i=0;i<7;i++){ cols[i] = col7[v*7+i]; vv[i] = val7[v*7+i]; }
  ushort8 g[7];
  #pragma unroll
  for (int i=0;i<7;i++) g[i] = *reinterpret_cast<const ushort8*>(base + (size_t)cols[i]*64);
  float acc[8];
  #pragma unroll
  for (int k=0;k<8;k++) acc[k] = 0.f;
  #pragma unroll
  for (int i=0;i<7;i++){
    float s = vv[i];
    #pragma unroll
    for (int k=0;k<8;k++) acc[k] += s*bf2f(g[i][k]);
  }
  ushort8 o;
  #pragma unroll
  for (int k=0;k<8;k++) o[k] = f2bf(acc[k]);
  *reinterpret_cast<ushort8*>(out + ((size_t)b*V + v)*64 + cg*8) = o;
}

// ---- MFMA dense linear (streaming rows): out = relu(in@W^T + d[v]*b), bf16 ----
template<int K, int N, bool RELU, bool DBIAS>
__global__ __launch_bounds__(256) void lin_mfma_k(const unsigned short* __restrict__ in,
    const float* __restrict__ W, const float* __restrict__ bias,
    unsigned short* __restrict__ out, int R, const float* __restrict__ dvec, int V){
  constexpr int KP = K + 8;
  constexpr int NF = N / 16;
  constexpr int KS = K / 32;
  __shared__ unsigned short sW[N * KP];
  __shared__ float sB[N];
  int tid = threadIdx.x;
  for (int i = tid*4; i < N*K; i += 1024){
    const float4 wv = *reinterpret_cast<const float4*>(W + i);
    int n = i / K, k = i - n*K;
    unsigned short* dst = &sW[n*KP + k];
    dst[0] = f2bf(wv.x); dst[1] = f2bf(wv.y); dst[2] = f2bf(wv.z); dst[3] = f2bf(wv.w);
  }
  if (tid < N) sB[tid] = bias[tid];
  __syncthreads();

  const int wave = tid >> 6, lane = tid & 63;
  const int l15 = lane & 15, lg = lane >> 4;
  const int rbase = blockIdx.x*128 + wave*32;

  int r0c = min(rbase + l15,      R-1);
  int r1c = min(rbase + 16 + l15, R-1);
  const unsigned short* bp0 = in + (size_t)r0c*K + lg*8;
  const unsigned short* bp1 = in + (size_t)r1c*K + lg*8;
  const unsigned short* aBase = &sW[l15*KP + lg*8];

  f32x4 acc[NF][2];
  #pragma unroll
  for (int nf=0; nf<NF; ++nf){ acc[nf][0] = (f32x4)0.f; acc[nf][1] = (f32x4)0.f; }

  #pragma unroll
  for (int ks=0; ks<KS; ++ks){
    short8v b0 = *reinterpret_cast<const short8v*>(bp0 + ks*32);
    short8v b1 = *reinterpret_cast<const short8v*>(bp1 + ks*32);
    #pragma unroll
    for (int nf=0; nf<NF; ++nf){
      short8v a = *reinterpret_cast<const short8v*>(aBase + nf*16*KP + ks*32);
      acc[nf][0] = __builtin_amdgcn_mfma_f32_16x16x32_bf16(a, b0, acc[nf][0], 0,0,0);
      acc[nf][1] = __builtin_amdgcn_mfma_f32_16x16x32_bf16(a, b1, acc[nf][1], 0,0,0);
    }
  }

  #pragma unroll
  for (int rr=0; rr<2; ++rr){
    int r = rbase + rr*16 + l15;
    if (r >= R) continue;
    float bscale = 1.f;
    if (DBIAS){ int vv = r % V; bscale = dvec[vv]; }
    #pragma unroll
    for (int nf=0; nf<NF; ++nf){
      int nb = nf*16 + lg*4;
      ushort4v o;
      #pragma unroll
      for (int reg=0; reg<4; ++reg){
        float v = acc[nf][rr][reg] + bscale*sB[nb + reg];
        if (RELU) v = v > 0.f ? v : 0.f;
        o[reg] = f2bf(v);
      }
      *reinterpret_cast<ushort4v*>(out + (size_t)r*N + nb) = o;
    }
  }
}

// ---- layer-3 linear + relu + mean-pool (streaming rows, NO h3 store) ----
__global__ __launch_bounds__(256) void lin3_mean_k(const unsigned short* __restrict__ in,
    const float* __restrict__ W, const float* __restrict__ bias,
    const float* __restrict__ dvec, float* __restrict__ g, int R, int V, int Bn){
  constexpr int K = 64, N = 128, KP = K + 8, NF = N/16, KS = K/32;
  __shared__ unsigned short sW[N * KP];
  __shared__ float sB[N];
  __shared__ float gPart[2][128];
  int tid = threadIdx.x;
  for (int i = tid*4; i < N*K; i += 1024){
    const float4 wv = *reinterpret_cast<const float4*>(W + i);
    int n = i / K, k = i - n*K;
    unsigned short* dst = &sW[n*KP + k];
    dst[0] = f2bf(wv.x); dst[1] = f2bf(wv.y); dst[2] = f2bf(wv.z); dst[3] = f2bf(wv.w);
  }
  if (tid < N) sB[tid] = bias[tid];
  if (tid < 128){ gPart[0][tid] = 0.f; gPart[1][tid] = 0.f; }
  __syncthreads();

  const int wave = tid >> 6, lane = tid & 63;
  const int l15 = lane & 15, lg = lane >> 4;
  const int rbase = blockIdx.x*128 + wave*32;

  int r0 = rbase + l15;
  int r1 = rbase + 16 + l15;
  int r0c = min(r0, R-1), r1c = min(r1, R-1);
  const unsigned short* bp0 = in + (size_t)r0c*K + lg*8;
  const unsigned short* bp1 = in + (size_t)r1c*K + lg*8;
  const unsigned short* aBase = &sW[l15*KP + lg*8];

  f32x4 acc[NF][2];
  #pragma unroll
  for (int nf=0; nf<NF; ++nf){ acc[nf][0] = (f32x4)0.f; acc[nf][1] = (f32x4)0.f; }

  #pragma unroll
  for (int ks=0; ks<KS; ++ks){
    short8v b0 = *reinterpret_cast<const short8v*>(bp0 + ks*32);
    short8v b1 = *reinterpret_cast<const short8v*>(bp1 + ks*32);
    #pragma unroll
    for (int nf=0; nf<NF; ++nf){
      short8v a = *reinterpret_cast<const short8v*>(aBase + nf*16*KP + ks*32);
      acc[nf][0] = __builtin_amdgcn_mfma_f32_16x16x32_bf16(a, b0, acc[nf][0], 0,0,0);
      acc[nf][1] = __builtin_amdgcn_mfma_f32_16x16x32_bf16(a, b1, acc[nf][1], 0,0,0);
    }
  }

  const int b0blk = (blockIdx.x*128) / V;
  bool ok0 = r0 < R, ok1 = r1 < R;
  int bb0 = r0c / V, bb1 = r1c / V;
  float d0 = dvec[r0c - bb0*V], d1 = dvec[r1c - bb1*V];
  bool in00 = ok0 && (bb0 == b0blk), in01 = ok0 && (bb0 == b0blk+1);
  bool in10 = ok1 && (bb1 == b0blk), in11 = ok1 && (bb1 == b0blk+1);

  #pragma unroll
  for (int nf=0; nf<NF; ++nf){
    #pragma unroll
    for (int reg=0; reg<4; ++reg){
      int c = nf*16 + lg*4 + reg;
      float v0 = fmaxf(acc[nf][0][reg] + d0*sB[c], 0.f);
      float v1 = fmaxf(acc[nf][1][reg] + d1*sB[c], 0.f);
      float sA = (in00 ? v0 : 0.f) + (in10 ? v1 : 0.f);
      float sBv= (in01 ? v0 : 0.f) + (in11 ? v1 : 0.f);
      #pragma unroll
      for (int m=1; m<16; m<<=1){
        sA  += __shfl_xor(sA,  m);
        sBv += __shfl_xor(sBv, m);
      }
      if (l15 == 0){
        atomicAdd(&gPart[0][c], sA);
        atomicAdd(&gPart[1][c], sBv);
      }
    }
  }
  __syncthreads();
  if (tid < 128){
    float a = gPart[0][tid];
    if (a != 0.f) atomicAdd(&g[b0blk*128 + tid], a);
    float b2 = gPart[1][tid];
    if (b2 != 0.f && b0blk+1 < Bn) atomicAdd(&g[(b0blk+1)*128 + tid], b2);
  }
}

// ---- fused VAE head: one block per batch element; emits mu, lv, zp ----
__global__ __launch_bounds__(256) void head2_k(const float* __restrict__ g,
    const float* __restrict__ Wfc, const float* __restrict__ bfc,
    const float* __restrict__ Wmu, const float* __restrict__ bmu,
    const float* __restrict__ Wlv, const float* __restrict__ blv,
    const float* __restrict__ eps, const float* __restrict__ Wd1,
    const float* __restrict__ bd1, float* __restrict__ mu_out,
    float* __restrict__ lv_out, float* __restrict__ zp, float invV){
  int b = blockIdx.x;
  int tid = threadIdx.x;
  __shared__ float sG[128];
  __shared__ float sF[256];
  __shared__ float sMu[32];
  __shared__ float sLv[32];
  __shared__ float sZ[32];
  if (tid < 128) sG[tid] = g[b*128 + tid] * invV;
  __syncthreads();
  {
    const float4* wr = reinterpret_cast<const float4*>(Wfc + tid*128);
    float acc = bfc[tid];
    #pragma unroll 8
    for (int k4=0;k4<32;k4++){
      float4 wv = wr[k4];
      acc += sG[k4*4]*wv.x + sG[k4*4+1]*wv.y + sG[k4*4+2]*wv.z + sG[k4*4+3]*wv.w;
    }
    sF[tid] = fmaxf(acc, 0.f);
  }
  __syncthreads();
  if (tid < 64){
    int c = tid & 31;
    bool isMu = tid < 32;
    const float4* wr = reinterpret_cast<const float4*>((isMu ? Wmu : Wlv) + c*256);
    float acc = isMu ? bmu[c] : blv[c];
    #pragma unroll 8
    for (int k4=0;k4<64;k4++){
      float4 wv = wr[k4];
      acc += sF[k4*4]*wv.x + sF[k4*4+1]*wv.y + sF[k4*4+2]*wv.z + sF[k4*4+3]*wv.w;
    }
    if (isMu){ sMu[c] = acc; mu_out[b*32+c] = acc; }
    else {
      acc = fminf(20.f, fmaxf(-20.f, acc));
      sLv[c] = acc; lv_out[b*32+c] = acc;
    }
  }
  __syncthreads();
  if (tid < 32) sZ[tid] = sMu[tid] + eps[b*32+tid]*expf(0.5f*sLv[tid]);
  __syncthreads();
  if (tid < 128){
    const float* wr = Wd1 + tid*35;
    float acc = bd1[tid];
    #pragma unroll
    for (int k=0;k<32;k++) acc += sZ[k]*wr[k];
    zp[b*128 + tid] = acc;
  }
}

// ---- FULL decoder in one kernel: hd1 built from zp+tmpl·Wd1tail -> dec2 (2 half-stages)
//      -> hd2 tile in LDS -> dec3 -> fused dec4 projection -> recon. No global intermediates.
__global__ __launch_bounds__(256) void dec_k(const float* __restrict__ zp,
    const float* __restrict__ tmpl, const float* __restrict__ Wd1,
    const float* __restrict__ Wd2, const float* __restrict__ bd2,
    const float* __restrict__ Wd3, const float* __restrict__ bd3,
    const float* __restrict__ Wd4, const float* __restrict__ bd4,
    float* __restrict__ out, int R, int V){
  constexpr int KP = 152;                       // 304B row: 16B-aligned, ~2-way banks
  __shared__ unsigned short sW[64*KP];          // Wd2-lo, then Wd2-hi, then Wd3 (re-staged)
  __shared__ unsigned short sH[128*KP];         // hd2 tile (bf16)
  __shared__ float sB2[128];
  __shared__ float sB3[64];
  __shared__ float sW4[192];
  __shared__ float sB4[3];
  __shared__ float sZP[16*128];
  __shared__ float sWT[128*3];
  int tid = threadIdx.x;

  if (tid < 128) sB2[tid] = bd2[tid];
  if (tid < 64)  sB3[tid] = bd3[tid];
  if (tid < 192) sW4[tid] = Wd4[tid];
  if (tid < 3)   sB4[tid] = bd4[tid];
  for (int i = tid; i < 16*128; i += 256) sZP[i] = zp[i];
  if (tid < 128){
    sWT[tid*3+0] = Wd1[tid*35+32];
    sWT[tid*3+1] = Wd1[tid*35+33];
    sWT[tid*3+2] = Wd1[tid*35+34];
  }
  // stage a 64x128 fp32 weight block into sW as bf16
  auto stageW = [&](const float* Wsrc){
    for (int i = tid*4; i < 64*128; i += 1024){
      float4 wv = *reinterpret_cast<const float4*>(Wsrc + i);
      int n = i >> 7, k = i & 127;
      unsigned short* dst = &sW[n*KP + k];
      dst[0]=f2bf(wv.x); dst[1]=f2bf(wv.y); dst[2]=f2bf(wv.z); dst[3]=f2bf(wv.w);
    }
  };
  stageW(Wd2);                       // rows 0..63
  __syncthreads();

  const int wave = tid >> 6, lane = tid & 63;
  const int l15 = lane & 15, lg = lane >> 4;
  const int rbase = blockIdx.x*128 + wave*32;
  const int lrow = wave*32;

  int r0c = min(rbase + l15,      R-1);
  int r1c = min(rbase + 16 + l15, R-1);
  int b0 = r0c / V, v0 = r0c - b0*V;
  int b1 = r1c / V, v1 = r1c - b1*V;
  float t0x=tmpl[v0*3], t0y=tmpl[v0*3+1], t0z=tmpl[v0*3+2];
  float t1x=tmpl[v1*3], t1y=tmpl[v1*3+1], t1z=tmpl[v1*3+2];

  // hd1 B-fragments (registers, reused by both dec2 halves)
  short8v bf0[4], bf1[4];
  #pragma unroll
  for (int ks=0; ks<4; ++ks){
    #pragma unroll
    for (int k=0;k<8;k++){
      int c = lg*8 + ks*32 + k;
      const float* wt = &sWT[c*3];
      float h0 = sZP[b0*128+c] + t0x*wt[0]+t0y*wt[1]+t0z*wt[2];
      float h1 = sZP[b1*128+c] + t1x*wt[0]+t1y*wt[1]+t1z*wt[2];
      bf0[ks][k] = (short)f2bf(fmaxf(h0,0.f));
      bf1[ks][k] = (short)f2bf(fmaxf(h1,0.f));
    }
  }

  const unsigned short* aBase = &sW[l15*KP + lg*8];

  // ---- dec2 in two N-halves (64 out-channels each) ----
  #pragma unroll
  for (int half=0; half<2; ++half){
    if (half==1){
      __syncthreads();
      stageW(Wd2 + 64*128);          // rows 64..127
      __syncthreads();
    }
    f32x4 acc[4][2];
    #pragma unroll
    for (int nf=0; nf<4; ++nf){ acc[nf][0]=(f32x4)0.f; acc[nf][1]=(f32x4)0.f; }
    #pragma unroll
    for (int ks=0; ks<4; ++ks){
      #pragma unroll
      for (int nf=0; nf<4; ++nf){
        short8v a = *reinterpret_cast<const short8v*>(aBase + nf*16*KP + ks*32);
        acc[nf][0] = __builtin_amdgcn_mfma_f32_16x16x32_bf16(a, bf0[ks], acc[nf][0], 0,0,0);
        acc[nf][1] = __builtin_amdgcn_mfma_f32_16x16x32_bf16(a, bf1[ks], acc[nf][1], 0,0,0);
      }
    }
    #pragma unroll
    for (int rr=0; rr<2; ++rr){
      #pragma unroll
      for (int nf=0; nf<4; ++nf){
        int c = half*64 + nf*16 + lg*4;
        ushort4v o;
        #pragma unroll
        for (int reg=0; reg<4; ++reg)
          o[reg] = f2bf(fmaxf(acc[nf][rr][reg] + sB2[c+reg], 0.f));
        *reinterpret_cast<ushort4v*>(&sH[(lrow + rr*16 + l15)*KP + c]) = o;
      }
    }
  }
  __syncthreads();
  stageW(Wd3);                        // 64x128
  __syncthreads();

  // ---- dec3 (K=128 from LDS hd2) ----
  f32x4 acc3[4][2];
  #pragma unroll
  for (int nf=0; nf<4; ++nf){ acc3[nf][0]=(f32x4)0.f; acc3[nf][1]=(f32x4)0.f; }
  #pragma unroll
  for (int ks=0; ks<4; ++ks){
    short8v h0 = *reinterpret_cast<const short8v*>(&sH[(lrow + l15)*KP + ks*32 + lg*8]);
    short8v h1 = *reinterpret_cast<const short8v*>(&sH[(lrow + 16 + l15)*KP + ks*32 + lg*8]);
    #pragma unroll
    for (int nf=0; nf<4; ++nf){
      short8v a = *reinterpret_cast<const short8v*>(aBase + nf*16*KP + ks*32);
      acc3[nf][0] = __builtin_amdgcn_mfma_f32_16x16x32_bf16(a, h0, acc3[nf][0], 0,0,0);
      acc3[nf][1] = __builtin_amdgcn_mfma_f32_16x16x32_bf16(a, h1, acc3[nf][1], 0,0,0);
    }
  }

  // ---- fused dec4: per-lane partial over its 16 channels, reduce across lg, store ----
  #pragma unroll
  for (int rr=0; rr<2; ++rr){
    int r = rbase + rr*16 + l15;
    float p0 = 0.f, p1 = 0.f, p2 = 0.f;
    #pragma unroll
    for (int nf=0; nf<4; ++nf){
      #pragma unroll
      for (int reg=0; reg<4; ++reg){
        int c = nf*16 + lg*4 + reg;
        float h = fmaxf(acc3[nf][rr][reg] + sB3[c], 0.f);
        p0 += h*sW4[c]; p1 += h*sW4[64+c]; p2 += h*sW4[128+c];
      }
    }
    p0 += __shfl_xor(p0,16); p0 += __shfl_xor(p0,32);
    p1 += __shfl_xor(p1,16); p1 += __shfl_xor(p1,32);
    p2 += __shfl_xor(p2,16); p2 += __shfl_xor(p2,32);
    if (lg == 0 && r < R){
      int v = rr ? v1 : v0;
      out[(size_t)r*3+0] = tmpl[v*3+0] + p0 + sB4[0];
      out[(size_t)r*3+1] = tmpl[v*3+1] + p1 + sB4[1];
      out[(size_t)r*3+2] = tmpl[v*3+2] + p2 + sB4[2];
    }
  }
}

extern "C" void kernel_launch(void* const* d_in, const int* in_sizes, int n_in,
                              void* d_out, int out_size, void* d_ws, size_t ws_size,
                              hipStream_t stream){
  const float* x    = (const float*)d_in[0];
  const float* eps  = (const float*)d_in[1];
  const int*   row  = (const int*)d_in[2];
  const int*   colx = (const int*)d_in[3];
  const float* vals = (const float*)d_in[4];
  const float* tmpl = (const float*)d_in[5];
  const float* W1 = (const float*)d_in[6];  const float* b1 = (const float*)d_in[7];
  const float* W2 = (const float*)d_in[8];  const float* b2 = (const float*)d_in[9];
  const float* W3 = (const float*)d_in[10]; const float* b3 = (const float*)d_in[11];
  const float* Wfc= (const float*)d_in[12]; const float* bfc= (const float*)d_in[13];
  const float* Wmu= (const float*)d_in[14]; const float* bmu= (const float*)d_in[15];
  const float* Wlv= (const float*)d_in[16]; const float* blv= (const float*)d_in[17];
  const float* Wd1= (const float*)d_in[18]; const float* bd1= (const float*)d_in[19];
  const float* Wd2= (const float*)d_in[20]; const float* bd2= (const float*)d_in[21];
  const float* Wd3= (const float*)d_in[22]; const float* bd3= (const float*)d_in[23];
  const float* Wd4= (const float*)d_in[24]; const float* bd4= (const float*)d_in[25];

  int V   = in_sizes[5] / 3;     // 10242
  int Bn  = in_sizes[1] / 32;    // 16
  int nnz = in_sizes[2];         // 71682
  int R   = Bn * V;              // 163872 (b-major rows: r = b*V + v)

  // workspace layout
  char* w = (char*)d_ws;
  size_t off = 0;
  auto alloc = [&](size_t bytes)->char*{
    char* p = w + off; off = (off + bytes + 255) & ~(size_t)255; return p;
  };
  unsigned short* bufA = (unsigned short*)alloc((size_t)R * 64 * 2);
  unsigned short* bufB = (unsigned short*)alloc((size_t)R * 64 * 2);
  int*   col7 = (int*)alloc((size_t)V*7*4);
  float* val7 = (float*)alloc((size_t)V*7*4);
  float* dvec = (float*)alloc((size_t)V*4);
  float* g    = (float*)alloc((size_t)Bn*128*4);
  float* zpb  = (float*)alloc((size_t)Bn*128*4);

  float* recon  = (float*)d_out;
  float* mu_out = recon + (size_t)R*3;
  float* lv_out = mu_out + (size_t)Bn*32;

  int mfmaGrid = (R + 127) / 128;
  int NBperB = (V*8 + 255) / 256;       // blocks per batch slice for spmm8s

  // prep (col7/val7/dvec + zero g)
  prep_k<<<(V+255)/256, 256, 0, stream>>>(row, colx, vals, nnz, col7, val7, dvec, g, V, Bn*128);

  // encoder
  spmm_lin1_k<<<(R+255)/256, 256, 0, stream>>>(x, col7, val7, dvec, W1, b1, bufA, V, R);
  spmm8s_k<<<16*NBperB, 256, 0, stream>>>(bufA, bufB, col7, val7, V, NBperB);
  lin_mfma_k<64,64,true,true><<<mfmaGrid, 256, 0, stream>>>(bufB, W2, b2, bufA, R, dvec, V);
  spmm8s_k<<<16*NBperB, 256, 0, stream>>>(bufA, bufB, col7, val7, V, NBperB);
  lin3_mean_k<<<mfmaGrid, 256, 0, stream>>>(bufB, W3, b3, dvec, g, R, V, Bn);

  // head (feat/mu/lv/z/zpart)
  head2_k<<<Bn, 256, 0, stream>>>(g, Wfc, bfc, Wmu, bmu, Wlv, blv, eps, Wd1, bd1,
                                  mu_out, lv_out, zpb, 1.0f/(float)V);

  // full decoder, single kernel
  dec_k<<<mfmaGrid, 256, 0, stream>>>(zpb, tmpl, Wd1, Wd2, bd2, Wd3, bd3, Wd4, bd4,
                                      recon, R, V);
}

// Round 9
// 131.884 us; speedup vs baseline: 1.4746x; 1.0997x over previous
//
#include <hip/hip_runtime.h>
#include <hip/hip_bf16.h>

typedef __attribute__((ext_vector_type(8))) unsigned short ushort8;
typedef __attribute__((ext_vector_type(4))) unsigned short ushort4v;
typedef __attribute__((ext_vector_type(8))) short short8v;
typedef __attribute__((ext_vector_type(4))) float f32x4;

__device__ __forceinline__ float bf2f(unsigned short u){
  union { unsigned int i; float f; } x; x.i = ((unsigned int)u) << 16; return x.f;
}
__device__ __forceinline__ unsigned short f2bf(float f){
  __hip_bfloat16 h = __float2bfloat16(f);
  return *reinterpret_cast<unsigned short*>(&h);
}

// XCD-affine block decode: p%8 = XCD slot; each XCD owns batches {xcd, xcd+8}.
// Grid must be 16*NB. Bijection [0,16*NB) -> (b, off).
__device__ __forceinline__ void sw_decode(int p, int NB, int& b, int& off){
  int xcd = p & 7, q = p >> 3;
  int hi = (q >= NB) ? 1 : 0;
  b = xcd + (hi << 3);
  off = q - (hi ? NB : 0);
}

// ---- prep: col7/val7/dvec via two binary searches over sorted row[]; zero g ----
__global__ void prep_k(const int* __restrict__ row, const int* __restrict__ colx,
                       const float* __restrict__ vals, int nnz,
                       int* __restrict__ col7, float* __restrict__ val7,
                       float* __restrict__ dvec, float* __restrict__ g, int V, int GN){
  int v = blockIdx.x*256 + threadIdx.x;
  if (v < GN) g[v] = 0.f;
  if (v >= V) return;
  int lo = 0, hi = nnz;
  while (lo < hi){ int m = (lo+hi)>>1; if (row[m] < v) lo = m+1; else hi = m; }
  int e0 = lo;
  int lo2 = e0; hi = nnz;
  while (lo2 < hi){ int m = (lo2+hi)>>1; if (row[m] < v+1) lo2 = m+1; else hi = m; }
  int e1 = lo2;
  float s = 0.f;
  #pragma unroll
  for (int i=0;i<7;i++){
    int e = e0 + i;
    int c  = (e < e1) ? colx[e] : 0;
    float wv = (e < e1) ? vals[e] : 0.f;
    col7[v*7+i] = c; val7[v*7+i] = wv; s += wv;
  }
  dvec[v] = s;
}

// ---- layer1 (XCD-affine): h1[b*V+v] = relu(spmm(x)@W1^T + d*b1) ----
__global__ void spmm_lin1_k(const float* __restrict__ x, const int* __restrict__ col7,
    const float* __restrict__ val7, const float* __restrict__ d,
    const float* __restrict__ W1, const float* __restrict__ b1,
    unsigned short* __restrict__ out, int V, int NB){
  __shared__ float sW[192];
  __shared__ float sB[64];
  int tid = threadIdx.x;
  if (tid < 192) sW[tid] = W1[tid];
  if (tid < 64)  sB[tid] = b1[tid];
  __syncthreads();
  int b, off; sw_decode(blockIdx.x, NB, b, off);
  int v = off*256 + tid;
  if (v >= V) return;
  const float* xb = x + (size_t)b*V*3;
  int   cs[7]; float ws[7];
  #pragma unroll
  for (int i=0;i<7;i++){ cs[i] = col7[v*7+i]; ws[i] = val7[v*7+i]; }
  float s0=0.f, s1=0.f, s2=0.f;
  #pragma unroll
  for (int i=0;i<7;i++){
    const float* xr = xb + (size_t)cs[i]*3;
    s0 += ws[i]*xr[0]; s1 += ws[i]*xr[1]; s2 += ws[i]*xr[2];
  }
  float dv = d[v];
  unsigned short* orow = out + ((size_t)b*V + v)*64;
  #pragma unroll
  for (int cg=0; cg<8; ++cg){
    ushort8 o;
    #pragma unroll
    for (int k=0;k<8;k++){
      int c = cg*8 + k;
      float acc = dv*sB[c] + s0*sW[c*3] + s1*sW[c*3+1] + s2*sW[c*3+2];
      o[k] = f2bf(fmaxf(acc, 0.f));
    }
    *reinterpret_cast<ushort8*>(orow + cg*8) = o;
  }
}

// ---- SPMM deg-7, 8ch/thread, XCD-affine ----
__global__ __launch_bounds__(256) void spmm8s_k(const unsigned short* __restrict__ in,
    unsigned short* __restrict__ out, const int* __restrict__ col7,
    const float* __restrict__ val7, int V, int NB){
  int b, off; sw_decode(blockIdx.x, NB, b, off);
  int j = off*256 + (int)threadIdx.x;
  if (j >= V*8) return;
  int cg = j & 7; int v = j >> 3;
  const unsigned short* base = in + (size_t)b*V*64 + cg*8;
  int cols[7]; float vv[7];
  #pragma unroll
  for (int i=0;i<7;i++){ cols[i] = col7[v*7+i]; vv[i] = val7[v*7+i]; }
  ushort8 g[7];
  #pragma unroll
  for (int i=0;i<7;i++) g[i] = *reinterpret_cast<const ushort8*>(base + (size_t)cols[i]*64);
  float acc[8];
  #pragma unroll
  for (int k=0;k<8;k++) acc[k] = 0.f;
  #pragma unroll
  for (int i=0;i<7;i++){
    float s = vv[i];
    #pragma unroll
    for (int k=0;k<8;k++) acc[k] += s*bf2f(g[i][k]);
  }
  ushort8 o;
  #pragma unroll
  for (int k=0;k<8;k++) o[k] = f2bf(acc[k]);
  *reinterpret_cast<ushort8*>(out + ((size_t)b*V + v)*64 + cg*8) = o;
}

// ---- MFMA dense linear, XCD-affine per-batch blocks: out = relu(in@W^T + d[v]*b) ----
template<int K, int N, bool RELU>
__global__ __launch_bounds__(256) void lin_mfma_k(const unsigned short* __restrict__ in,
    const float* __restrict__ W, const float* __restrict__ bias,
    unsigned short* __restrict__ out, const float* __restrict__ dvec, int V, int NB){
  constexpr int KP = K + 8;
  constexpr int NF = N / 16;
  constexpr int KS = K / 32;
  __shared__ unsigned short sW[N * KP];
  __shared__ float sB[N];
  int tid = threadIdx.x;
  for (int i = tid*4; i < N*K; i += 1024){
    const float4 wv = *reinterpret_cast<const float4*>(W + i);
    int n = i / K, k = i - n*K;
    unsigned short* dst = &sW[n*KP + k];
    dst[0] = f2bf(wv.x); dst[1] = f2bf(wv.y); dst[2] = f2bf(wv.z); dst[3] = f2bf(wv.w);
  }
  if (tid < N) sB[tid] = bias[tid];
  __syncthreads();

  int b, off; sw_decode(blockIdx.x, NB, b, off);
  const int wave = tid >> 6, lane = tid & 63;
  const int l15 = lane & 15, lg = lane >> 4;
  const int vbase = off*128 + wave*32;

  int v0r = vbase + l15, v1r = vbase + 16 + l15;
  int v0c = min(v0r, V-1), v1c = min(v1r, V-1);
  const size_t bb = (size_t)b*V;
  const unsigned short* bp0 = in + (bb + v0c)*K + lg*8;
  const unsigned short* bp1 = in + (bb + v1c)*K + lg*8;
  const unsigned short* aBase = &sW[l15*KP + lg*8];

  f32x4 acc[NF][2];
  #pragma unroll
  for (int nf=0; nf<NF; ++nf){ acc[nf][0] = (f32x4)0.f; acc[nf][1] = (f32x4)0.f; }

  #pragma unroll
  for (int ks=0; ks<KS; ++ks){
    short8v b0 = *reinterpret_cast<const short8v*>(bp0 + ks*32);
    short8v b1 = *reinterpret_cast<const short8v*>(bp1 + ks*32);
    #pragma unroll
    for (int nf=0; nf<NF; ++nf){
      short8v a = *reinterpret_cast<const short8v*>(aBase + nf*16*KP + ks*32);
      acc[nf][0] = __builtin_amdgcn_mfma_f32_16x16x32_bf16(a, b0, acc[nf][0], 0,0,0);
      acc[nf][1] = __builtin_amdgcn_mfma_f32_16x16x32_bf16(a, b1, acc[nf][1], 0,0,0);
    }
  }

  float d0 = dvec[v0c], d1 = dvec[v1c];
  #pragma unroll
  for (int rr=0; rr<2; ++rr){
    int v = rr ? v1r : v0r;
    if (v >= V) continue;
    float ds = rr ? d1 : d0;
    #pragma unroll
    for (int nf=0; nf<NF; ++nf){
      int nb = nf*16 + lg*4;
      ushort4v o;
      #pragma unroll
      for (int reg=0; reg<4; ++reg){
        float val = acc[nf][rr][reg] + ds*sB[nb + reg];
        if (RELU) val = val > 0.f ? val : 0.f;
        o[reg] = f2bf(val);
      }
      *reinterpret_cast<ushort4v*>(out + (bb + v)*N + nb) = o;
    }
  }
}

// ---- layer-3 linear + relu + mean-pool, XCD-affine (single batch per block) ----
__global__ __launch_bounds__(256) void lin3_mean_k(const unsigned short* __restrict__ in,
    const float* __restrict__ W, const float* __restrict__ bias,
    const float* __restrict__ dvec, float* __restrict__ g, int V, int NB){
  constexpr int K = 64, N = 128, KP = K + 8, NF = N/16, KS = K/32;
  __shared__ unsigned short sW[N * KP];
  __shared__ float sB[N];
  __shared__ float gPart[128];
  int tid = threadIdx.x;
  for (int i = tid*4; i < N*K; i += 1024){
    const float4 wv = *reinterpret_cast<const float4*>(W + i);
    int n = i / K, k = i - n*K;
    unsigned short* dst = &sW[n*KP + k];
    dst[0] = f2bf(wv.x); dst[1] = f2bf(wv.y); dst[2] = f2bf(wv.z); dst[3] = f2bf(wv.w);
  }
  if (tid < N) sB[tid] = bias[tid];
  if (tid < 128) gPart[tid] = 0.f;
  __syncthreads();

  int b, off; sw_decode(blockIdx.x, NB, b, off);
  const int wave = tid >> 6, lane = tid & 63;
  const int l15 = lane & 15, lg = lane >> 4;
  const int vbase = off*128 + wave*32;

  int v0r = vbase + l15, v1r = vbase + 16 + l15;
  int v0c = min(v0r, V-1), v1c = min(v1r, V-1);
  const size_t bb = (size_t)b*V;
  const unsigned short* bp0 = in + (bb + v0c)*K + lg*8;
  const unsigned short* bp1 = in + (bb + v1c)*K + lg*8;
  const unsigned short* aBase = &sW[l15*KP + lg*8];

  f32x4 acc[NF][2];
  #pragma unroll
  for (int nf=0; nf<NF; ++nf){ acc[nf][0] = (f32x4)0.f; acc[nf][1] = (f32x4)0.f; }

  #pragma unroll
  for (int ks=0; ks<KS; ++ks){
    short8v b0 = *reinterpret_cast<const short8v*>(bp0 + ks*32);
    short8v b1 = *reinterpret_cast<const short8v*>(bp1 + ks*32);
    #pragma unroll
    for (int nf=0; nf<NF; ++nf){
      short8v a = *reinterpret_cast<const short8v*>(aBase + nf*16*KP + ks*32);
      acc[nf][0] = __builtin_amdgcn_mfma_f32_16x16x32_bf16(a, b0, acc[nf][0], 0,0,0);
      acc[nf][1] = __builtin_amdgcn_mfma_f32_16x16x32_bf16(a, b1, acc[nf][1], 0,0,0);
    }
  }

  bool ok0 = v0r < V, ok1 = v1r < V;
  float d0 = dvec[v0c], d1 = dvec[v1c];
  #pragma unroll
  for (int nf=0; nf<NF; ++nf){
    #pragma unroll
    for (int reg=0; reg<4; ++reg){
      int c = nf*16 + lg*4 + reg;
      float v0f = fmaxf(acc[nf][0][reg] + d0*sB[c], 0.f);
      float v1f = fmaxf(acc[nf][1][reg] + d1*sB[c], 0.f);
      float sA = (ok0 ? v0f : 0.f) + (ok1 ? v1f : 0.f);
      #pragma unroll
      for (int m=1; m<16; m<<=1) sA += __shfl_xor(sA, m);
      if (l15 == 0) atomicAdd(&gPart[c], sA);
    }
  }
  __syncthreads();
  if (tid < 128){
    float a = gPart[tid];
    if (a != 0.f) atomicAdd(&g[b*128 + tid], a);
  }
}

// ---- fused VAE head: one block per batch element; emits mu, lv, zp ----
__global__ __launch_bounds__(256) void head2_k(const float* __restrict__ g,
    const float* __restrict__ Wfc, const float* __restrict__ bfc,
    const float* __restrict__ Wmu, const float* __restrict__ bmu,
    const float* __restrict__ Wlv, const float* __restrict__ blv,
    const float* __restrict__ eps, const float* __restrict__ Wd1,
    const float* __restrict__ bd1, float* __restrict__ mu_out,
    float* __restrict__ lv_out, float* __restrict__ zp, float invV){
  int b = blockIdx.x;
  int tid = threadIdx.x;
  __shared__ float sG[128];
  __shared__ float sF[256];
  __shared__ float sMu[32];
  __shared__ float sLv[32];
  __shared__ float sZ[32];
  if (tid < 128) sG[tid] = g[b*128 + tid] * invV;
  __syncthreads();
  {
    const float4* wr = reinterpret_cast<const float4*>(Wfc + tid*128);
    float acc = bfc[tid];
    #pragma unroll 8
    for (int k4=0;k4<32;k4++){
      float4 wv = wr[k4];
      acc += sG[k4*4]*wv.x + sG[k4*4+1]*wv.y + sG[k4*4+2]*wv.z + sG[k4*4+3]*wv.w;
    }
    sF[tid] = fmaxf(acc, 0.f);
  }
  __syncthreads();
  if (tid < 64){
    int c = tid & 31;
    bool isMu = tid < 32;
    const float4* wr = reinterpret_cast<const float4*>((isMu ? Wmu : Wlv) + c*256);
    float acc = isMu ? bmu[c] : blv[c];
    #pragma unroll 8
    for (int k4=0;k4<64;k4++){
      float4 wv = wr[k4];
      acc += sF[k4*4]*wv.x + sF[k4*4+1]*wv.y + sF[k4*4+2]*wv.z + sF[k4*4+3]*wv.w;
    }
    if (isMu){ sMu[c] = acc; mu_out[b*32+c] = acc; }
    else {
      acc = fminf(20.f, fmaxf(-20.f, acc));
      sLv[c] = acc; lv_out[b*32+c] = acc;
    }
  }
  __syncthreads();
  if (tid < 32) sZ[tid] = sMu[tid] + eps[b*32+tid]*expf(0.5f*sLv[tid]);
  __syncthreads();
  if (tid < 128){
    const float* wr = Wd1 + tid*35;
    float acc = bd1[tid];
    #pragma unroll
    for (int k=0;k<32;k++) acc += sZ[k]*wr[k];
    zp[b*128 + tid] = acc;
  }
}

// ---- FULL decoder, XCD-affine per-batch blocks ----
__global__ __launch_bounds__(256) void dec_k(const float* __restrict__ zp,
    const float* __restrict__ tmpl, const float* __restrict__ Wd1,
    const float* __restrict__ Wd2, const float* __restrict__ bd2,
    const float* __restrict__ Wd3, const float* __restrict__ bd3,
    const float* __restrict__ Wd4, const float* __restrict__ bd4,
    float* __restrict__ out, int V, int NB){
  constexpr int KP = 152;
  __shared__ unsigned short sW[64*KP];
  __shared__ unsigned short sH[128*KP];
  __shared__ float sB2[128];
  __shared__ float sB3[64];
  __shared__ float sW4[192];
  __shared__ float sB4[3];
  __shared__ float sZPb[128];
  __shared__ float sWT[128*3];
  int tid = threadIdx.x;
  int b, off; sw_decode(blockIdx.x, NB, b, off);

  if (tid < 128) sB2[tid] = bd2[tid];
  if (tid < 64)  sB3[tid] = bd3[tid];
  if (tid < 192) sW4[tid] = Wd4[tid];
  if (tid < 3)   sB4[tid] = bd4[tid];
  if (tid < 128) sZPb[tid] = zp[b*128 + tid];
  if (tid < 128){
    sWT[tid*3+0] = Wd1[tid*35+32];
    sWT[tid*3+1] = Wd1[tid*35+33];
    sWT[tid*3+2] = Wd1[tid*35+34];
  }
  auto stageW = [&](const float* Wsrc){
    for (int i = tid*4; i < 64*128; i += 1024){
      float4 wv = *reinterpret_cast<const float4*>(Wsrc + i);
      int n = i >> 7, k = i & 127;
      unsigned short* dst = &sW[n*KP + k];
      dst[0]=f2bf(wv.x); dst[1]=f2bf(wv.y); dst[2]=f2bf(wv.z); dst[3]=f2bf(wv.w);
    }
  };
  stageW(Wd2);
  __syncthreads();

  const int wave = tid >> 6, lane = tid & 63;
  const int l15 = lane & 15, lg = lane >> 4;
  const int vbase = off*128 + wave*32;
  const int lrow = wave*32;

  int v0r = vbase + l15, v1r = vbase + 16 + l15;
  int v0 = min(v0r, V-1), v1 = min(v1r, V-1);
  float t0x=tmpl[v0*3], t0y=tmpl[v0*3+1], t0z=tmpl[v0*3+2];
  float t1x=tmpl[v1*3], t1y=tmpl[v1*3+1], t1z=tmpl[v1*3+2];

  short8v bf0[4], bf1[4];
  #pragma unroll
  for (int ks=0; ks<4; ++ks){
    #pragma unroll
    for (int k=0;k<8;k++){
      int c = lg*8 + ks*32 + k;
      const float* wt = &sWT[c*3];
      float zc = sZPb[c];
      bf0[ks][k] = (short)f2bf(fmaxf(zc + t0x*wt[0]+t0y*wt[1]+t0z*wt[2], 0.f));
      bf1[ks][k] = (short)f2bf(fmaxf(zc + t1x*wt[0]+t1y*wt[1]+t1z*wt[2], 0.f));
    }
  }

  const unsigned short* aBase = &sW[l15*KP + lg*8];

  #pragma unroll
  for (int half=0; half<2; ++half){
    if (half==1){
      __syncthreads();
      stageW(Wd2 + 64*128);
      __syncthreads();
    }
    f32x4 acc[4][2];
    #pragma unroll
    for (int nf=0; nf<4; ++nf){ acc[nf][0]=(f32x4)0.f; acc[nf][1]=(f32x4)0.f; }
    #pragma unroll
    for (int ks=0; ks<4; ++ks){
      #pragma unroll
      for (int nf=0; nf<4; ++nf){
        short8v a = *reinterpret_cast<const short8v*>(aBase + nf*16*KP + ks*32);
        acc[nf][0] = __builtin_amdgcn_mfma_f32_16x16x32_bf16(a, bf0[ks], acc[nf][0], 0,0,0);
        acc[nf][1] = __builtin_amdgcn_mfma_f32_16x16x32_bf16(a, bf1[ks], acc[nf][1], 0,0,0);
      }
    }
    #pragma unroll
    for (int rr=0; rr<2; ++rr){
      #pragma unroll
      for (int nf=0; nf<4; ++nf){
        int c = half*64 + nf*16 + lg*4;
        ushort4v o;
        #pragma unroll
        for (int reg=0; reg<4; ++reg)
          o[reg] = f2bf(fmaxf(acc[nf][rr][reg] + sB2[c+reg], 0.f));
        *reinterpret_cast<ushort4v*>(&sH[(lrow + rr*16 + l15)*KP + c]) = o;
      }
    }
  }
  __syncthreads();
  stageW(Wd3);
  __syncthreads();

  f32x4 acc3[4][2];
  #pragma unroll
  for (int nf=0; nf<4; ++nf){ acc3[nf][0]=(f32x4)0.f; acc3[nf][1]=(f32x4)0.f; }
  #pragma unroll
  for (int ks=0; ks<4; ++ks){
    short8v h0 = *reinterpret_cast<const short8v*>(&sH[(lrow + l15)*KP + ks*32 + lg*8]);
    short8v h1 = *reinterpret_cast<const short8v*>(&sH[(lrow + 16 + l15)*KP + ks*32 + lg*8]);
    #pragma unroll
    for (int nf=0; nf<4; ++nf){
      short8v a = *reinterpret_cast<const short8v*>(aBase + nf*16*KP + ks*32);
      acc3[nf][0] = __builtin_amdgcn_mfma_f32_16x16x32_bf16(a, h0, acc3[nf][0], 0,0,0);
      acc3[nf][1] = __builtin_amdgcn_mfma_f32_16x16x32_bf16(a, h1, acc3[nf][1], 0,0,0);
    }
  }

  #pragma unroll
  for (int rr=0; rr<2; ++rr){
    int vr = rr ? v1r : v0r;
    float p0 = 0.f, p1 = 0.f, p2 = 0.f;
    #pragma unroll
    for (int nf=0; nf<4; ++nf){
      #pragma unroll
      for (int reg=0; reg<4; ++reg){
        int c = nf*16 + lg*4 + reg;
        float h = fmaxf(acc3[nf][rr][reg] + sB3[c], 0.f);
        p0 += h*sW4[c]; p1 += h*sW4[64+c]; p2 += h*sW4[128+c];
      }
    }
    p0 += __shfl_xor(p0,16); p0 += __shfl_xor(p0,32);
    p1 += __shfl_xor(p1,16); p1 += __shfl_xor(p1,32);
    p2 += __shfl_xor(p2,16); p2 += __shfl_xor(p2,32);
    if (lg == 0 && vr < V){
      size_t o = ((size_t)b*V + vr)*3;
      out[o+0] = tmpl[vr*3+0] + p0 + sB4[0];
      out[o+1] = tmpl[vr*3+1] + p1 + sB4[1];
      out[o+2] = tmpl[vr*3+2] + p2 + sB4[2];
    }
  }
}

extern "C" void kernel_launch(void* const* d_in, const int* in_sizes, int n_in,
                              void* d_out, int out_size, void* d_ws, size_t ws_size,
                              hipStream_t stream){
  const float* x    = (const float*)d_in[0];
  const float* eps  = (const float*)d_in[1];
  const int*   row  = (const int*)d_in[2];
  const int*   colx = (const int*)d_in[3];
  const float* vals = (const float*)d_in[4];
  const float* tmpl = (const float*)d_in[5];
  const float* W1 = (const float*)d_in[6];  const float* b1 = (const float*)d_in[7];
  const float* W2 = (const float*)d_in[8];  const float* b2 = (const float*)d_in[9];
  const float* W3 = (const float*)d_in[10]; const float* b3 = (const float*)d_in[11];
  const float* Wfc= (const float*)d_in[12]; const float* bfc= (const float*)d_in[13];
  const float* Wmu= (const float*)d_in[14]; const float* bmu= (const float*)d_in[15];
  const float* Wlv= (const float*)d_in[16]; const float* blv= (const float*)d_in[17];
  const float* Wd1= (const float*)d_in[18]; const float* bd1= (const float*)d_in[19];
  const float* Wd2= (const float*)d_in[20]; const float* bd2= (const float*)d_in[21];
  const float* Wd3= (const float*)d_in[22]; const float* bd3= (const float*)d_in[23];
  const float* Wd4= (const float*)d_in[24]; const float* bd4= (const float*)d_in[25];

  int V   = in_sizes[5] / 3;     // 10242
  int Bn  = in_sizes[1] / 32;    // 16
  int nnz = in_sizes[2];         // 71682
  int R   = Bn * V;              // 163872 (b-major rows: r = b*V + v)

  // workspace layout
  char* w = (char*)d_ws;
  size_t off = 0;
  auto alloc = [&](size_t bytes)->char*{
    char* p = w + off; off = (off + bytes + 255) & ~(size_t)255; return p;
  };
  unsigned short* bufA = (unsigned short*)alloc((size_t)R * 64 * 2);
  unsigned short* bufB = (unsigned short*)alloc((size_t)R * 64 * 2);
  int*   col7 = (int*)alloc((size_t)V*7*4);
  float* val7 = (float*)alloc((size_t)V*7*4);
  float* dvec = (float*)alloc((size_t)V*4);
  float* g    = (float*)alloc((size_t)Bn*128*4);
  float* zpb  = (float*)alloc((size_t)Bn*128*4);

  float* recon  = (float*)d_out;
  float* mu_out = recon + (size_t)R*3;
  float* lv_out = mu_out + (size_t)Bn*32;

  int NB1 = (V + 255) / 256;       // spmm_lin1: 256 rows/block
  int NB8 = (V*8 + 255) / 256;     // spmm8s: 32 rows/block
  int NBm = (V + 127) / 128;       // MFMA kernels: 128 rows/block

  // prep (col7/val7/dvec + zero g)
  prep_k<<<(V+255)/256, 256, 0, stream>>>(row, colx, vals, nnz, col7, val7, dvec, g, V, Bn*128);

  // encoder (all XCD-affine: batch b on XCD b%8)
  spmm_lin1_k<<<16*NB1, 256, 0, stream>>>(x, col7, val7, dvec, W1, b1, bufA, V, NB1);
  spmm8s_k<<<16*NB8, 256, 0, stream>>>(bufA, bufB, col7, val7, V, NB8);
  lin_mfma_k<64,64,true><<<16*NBm, 256, 0, stream>>>(bufB, W2, b2, bufA, dvec, V, NBm);
  spmm8s_k<<<16*NB8, 256, 0, stream>>>(bufA, bufB, col7, val7, V, NB8);
  lin3_mean_k<<<16*NBm, 256, 0, stream>>>(bufB, W3, b3, dvec, g, V, NBm);

  // head (feat/mu/lv/z/zpart)
  head2_k<<<Bn, 256, 0, stream>>>(g, Wfc, bfc, Wmu, bmu, Wlv, blv, eps, Wd1, bd1,
                                  mu_out, lv_out, zpb, 1.0f/(float)V);

  // full decoder, single kernel, XCD-affine
  dec_k<<<16*NBm, 256, 0, stream>>>(zpb, tmpl, Wd1, Wd2, bd2, Wd3, bd3, Wd4, bd4,
                                    recon, V, NBm);
}